// Round 6
// baseline (168.549 us; speedup 1.0000x reference)
//
#include <hip/hip_runtime.h>
#include <hip/hip_bf16.h>

#define NH 12
#define HD 64
#define SEQ 2048
#define DM 768

typedef __attribute__((ext_vector_type(8))) short bf16x8;
typedef __attribute__((ext_vector_type(4))) short bf16x4;
typedef __attribute__((ext_vector_type(4))) float f32x4;

static __device__ __forceinline__ unsigned short f2bf(float f) {
  unsigned int u = __float_as_uint(f);
  u += 0x7fff + ((u >> 16) & 1);   // round-to-nearest-even
  return (unsigned short)(u >> 16);
}

static __device__ __forceinline__ unsigned cvt_pk_bf16(float lo, float hi) {
  unsigned r;
  asm("v_cvt_pk_bf16_f32 %0, %1, %2" : "=v"(r) : "v"(lo), "v"(hi));
  return r;
}

static __device__ __forceinline__ void gload_lds16(const void* g, void* l) {
  __builtin_amdgcn_global_load_lds(
      (const __attribute__((address_space(1))) void*)g,
      (__attribute__((address_space(3))) void*)l, 16, 0, 0);
}

static __device__ __forceinline__ bf16x8 cat4(bf16x4 a, bf16x4 b) {
  bf16x8 r;
  r[0] = a[0]; r[1] = a[1]; r[2] = a[2]; r[3] = a[3];
  r[4] = b[0]; r[5] = b[1]; r[6] = b[2]; r[7] = b[3];
  return r;
}

// q-store scale: sqrt(log2(e))/8 — folds the 1/64 attention scale and the
// base-2 exp conversion into q at the QKV store.
#define QSCALE 0.15014030f

// ---------------------------------------------------------------------------
// Kernel 0: f32 -> bf16 bulk convert (vector x8), grid-stride.
// ---------------------------------------------------------------------------
__global__ __launch_bounds__(256) void cvt_kernel(
    const float* __restrict__ src, unsigned short* __restrict__ dst, int n8) {
  int i = blockIdx.x * 256 + threadIdx.x;
  const int stride = gridDim.x * 256;
  for (; i < n8; i += stride) {
    const float4 a = reinterpret_cast<const float4*>(src)[i * 2];
    const float4 b = reinterpret_cast<const float4*>(src)[i * 2 + 1];
    ushort4 lo = make_ushort4(f2bf(a.x), f2bf(a.y), f2bf(a.z), f2bf(a.w));
    ushort4 hi = make_ushort4(f2bf(b.x), f2bf(b.y), f2bf(b.z), f2bf(b.w));
    reinterpret_cast<ushort4*>(dst)[i * 2] = lo;
    reinterpret_cast<ushort4*>(dst)[i * 2 + 1] = hi;
  }
}

// ---------------------------------------------------------------------------
// Kernel 1: qkv = xb @ wb^T + b (bf16 inputs). q stored (B,H,S,HD) bf16
// PRE-SCALED by QSCALE; v stored transposed (B,H,HD,S) bf16.
// ---------------------------------------------------------------------------
__global__ __launch_bounds__(256) void qkv_kernel(
    const unsigned short* __restrict__ xb, const unsigned short* __restrict__ wb,
    const float* __restrict__ bias,
    unsigned short* __restrict__ qb, unsigned short* __restrict__ vtb) {
  __shared__ alignas(16) unsigned short As[128 * 40];
  __shared__ alignas(16) unsigned short Bs[128 * 40];
  const int tid = threadIdx.x;
  const int lane = tid & 63, wid = tid >> 6;
  const int wr = wid >> 1, wc = wid & 1;
  const int g = lane >> 4, c = lane & 15;
  const int m0 = blockIdx.x * 128, n0 = blockIdx.y * 128;

  f32x4 acc[4][4] = {};

  for (int k0 = 0; k0 < DM; k0 += 32) {
#pragma unroll
    for (int i = 0; i < 2; ++i) {  // A+B: pure bf16 vector copies
      const int idx = tid + i * 256;
      const int row = idx >> 2, kq = (idx & 3) << 3;
      *reinterpret_cast<bf16x8*>(&As[row * 40 + kq]) =
          *reinterpret_cast<const bf16x8*>(&xb[(m0 + row) * DM + k0 + kq]);
      *reinterpret_cast<bf16x8*>(&Bs[row * 40 + kq]) =
          *reinterpret_cast<const bf16x8*>(&wb[(n0 + row) * DM + k0 + kq]);
    }
    __syncthreads();
    bf16x8 a_f[4], b_f[4];
#pragma unroll
    for (int i = 0; i < 4; ++i) {
      a_f[i] = *reinterpret_cast<const bf16x8*>(&As[(wr * 64 + i * 16 + c) * 40 + g * 8]);
      b_f[i] = *reinterpret_cast<const bf16x8*>(&Bs[(wc * 64 + i * 16 + c) * 40 + g * 8]);
    }
#pragma unroll
    for (int ai = 0; ai < 4; ++ai)
#pragma unroll
      for (int ni = 0; ni < 4; ++ni)
        acc[ai][ni] = __builtin_amdgcn_mfma_f32_16x16x32_bf16(a_f[ai], b_f[ni], acc[ai][ni], 0, 0, 0);
    __syncthreads();
  }

#pragma unroll
  for (int ni = 0; ni < 4; ++ni) {
    const int n = n0 + wc * 64 + ni * 16 + c;
    const float bn = bias[n];
    if (n < DM) {  // q path: (B,H,S,HD), pre-scaled
      const int h = n >> 6, d = n & 63;
#pragma unroll
      for (int ai = 0; ai < 4; ++ai)
#pragma unroll
        for (int r = 0; r < 4; ++r) {
          const int m = m0 + wr * 64 + ai * 16 + g * 4 + r;
          const int bb = m >> 11, s = m & 2047;
          qb[(((size_t)(bb * NH + h)) * SEQ + s) * HD + d] = f2bf((acc[ai][ni][r] + bn) * QSCALE);
        }
    } else {  // v path: transposed (B,H,HD,S)
      const int nn = n - DM;
      const int h = nn >> 6, d = nn & 63;
#pragma unroll
      for (int ai = 0; ai < 4; ++ai) {
        const int m_base = m0 + wr * 64 + ai * 16 + g * 4;
        const int bb = m_base >> 11, s0 = m_base & 2047;
        ushort4 pk = make_ushort4(f2bf(acc[ai][ni][0] + bn), f2bf(acc[ai][ni][1] + bn),
                                  f2bf(acc[ai][ni][2] + bn), f2bf(acc[ai][ni][3] + bn));
        *reinterpret_cast<ushort4*>(
            &vtb[((size_t)(bb * NH + h) * HD + d) * SEQ + s0]) = pk;
      }
    }
  }
}

// ---------------------------------------------------------------------------
// Kernel 2: flash attention, Q == K (pre-scaled), FIXED-max base-2 softmax.
// 128 q-rows per block (qf[8][2] in regs); wave wid owns k-rows [wid*16,+16)
// of each 64-row K-tile -> wave-private LDS strips, NO barriers in main loop.
// Triple-buffered global_load_lds staging (vmcnt counted at 8, never 0) PLUS
// register-level ds_read prefetch one tile ahead. PV pair-merged into K=32.
// ---------------------------------------------------------------------------
__global__ __launch_bounds__(256) void attn_kernel(
    const unsigned short* __restrict__ qb, const unsigned short* __restrict__ vtb,
    unsigned short* __restrict__ ao) {
  __shared__ alignas(16) char pool[49152];   // 3 bufs x (4 waves x 4KB); epilogue reuses

  const int tid = threadIdx.x;
  const int lane = tid & 63, wid = tid >> 6;
  const int g = lane >> 4, c = lane & 15;
  const int bh = blockIdx.y;
  const int qs0 = blockIdx.x * 128;
  const size_t base = (size_t)bh * SEQ * HD;

  // Q B-frags: lane (c,g) holds Q[qs0+jq*16+c][ks*32+g*8..+7]
  bf16x8 qf[8][2];
#pragma unroll
  for (int jq = 0; jq < 8; ++jq) {
    const unsigned short* qrow = &qb[base + (size_t)(qs0 + jq * 16 + c) * HD + g * 8];
    qf[jq][0] = *reinterpret_cast<const bf16x8*>(qrow);
    qf[jq][1] = *reinterpret_cast<const bf16x8*>(qrow + 32);
  }

  const char* qbB = (const char*)qb;
  const char* vtB = (const char*)vtb;
  auto bufp = [&](int b) -> char* { return pool + b * 16384 + wid * 4096; };
  // Stage tile kt's quarter for THIS wave into buffer buf (wave-private strip).
  auto stage = [&](int kt, int buf) {
    char* strip = bufp(buf);
    const size_t kQ = (base + (size_t)(kt * 64 + wid * 16) * HD) * 2;
#pragma unroll
    for (int i = 0; i < 2; ++i) {
      const int o = i * 1024 + lane * 16;
      const int swz = o ^ (((o >> 7) & 7) << 4);
      gload_lds16(qbB + kQ + swz, strip + o);
    }
#pragma unroll
    for (int i = 0; i < 2; ++i) {
      const int o = i * 1024 + lane * 16;
      const int row = o >> 5, half = (o >> 4) & 1;
      const int srcoff = (half ^ ((row >> 2) & 1)) << 4;
      gload_lds16(vtB + ((size_t)(bh * HD + row) * SEQ) * 2 + (size_t)kt * 128 + wid * 32 + srcoff,
                  strip + 2048 + o);
    }
  };

  const int cswz = (c & 7) << 4;
  const int vswz = (g * 8) ^ (((c >> 2) & 1) << 4);
  auto loadK = [&](const char* strip, bf16x8* kf) {
    kf[0] = *reinterpret_cast<const bf16x8*>(strip + c * 128 + ((g * 16) ^ cswz));
    kf[1] = *reinterpret_cast<const bf16x8*>(strip + c * 128 + ((64 + g * 16) ^ cswz));
  };
  auto loadV = [&](const char* strip, bf16x4* vf) {
#pragma unroll
    for (int dn = 0; dn < 4; ++dn)
      vf[dn] = *reinterpret_cast<const bf16x4*>(strip + 2048 + (dn * 16 + c) * 32 + vswz);
  };

  float l_p[8] = {};
  f32x4 o_acc[4][8] = {};  // [dn][jq]: O[d=dn*16+4g+r][q=jq*16+c], partial over wid's k

  auto qk = [&](const bf16x8* kf, f32x4* s) {
    __builtin_amdgcn_s_setprio(1);
#pragma unroll
    for (int jq = 0; jq < 8; ++jq)
      s[jq] = __builtin_amdgcn_mfma_f32_16x16x32_bf16(kf[0], qf[jq][0], s[jq], 0, 0, 0);
#pragma unroll
    for (int jq = 0; jq < 8; ++jq)
      s[jq] = __builtin_amdgcn_mfma_f32_16x16x32_bf16(kf[1], qf[jq][1], s[jq], 0, 0, 0);
    __builtin_amdgcn_s_setprio(0);
  };
  auto expcvt = [&](const f32x4* s, bf16x4* pb) {
#pragma unroll
    for (int jq = 0; jq < 8; ++jq) {
      float p0 = __builtin_amdgcn_exp2f(s[jq][0]);
      float p1 = __builtin_amdgcn_exp2f(s[jq][1]);
      float p2 = __builtin_amdgcn_exp2f(s[jq][2]);
      float p3 = __builtin_amdgcn_exp2f(s[jq][3]);
      l_p[jq] += (p0 + p1) + (p2 + p3);
      uint2 wv = make_uint2(cvt_pk_bf16(p0, p1), cvt_pk_bf16(p2, p3));
      pb[jq] = *reinterpret_cast<bf16x4*>(&wv);
    }
  };

  bf16x8 kf0[2], kf1[2], kfn[2];
  bf16x4 vf0[4], vf1[4], vfn[4];

  stage(0, 0); stage(1, 1); stage(2, 2);
  asm volatile("s_waitcnt vmcnt(8)" ::: "memory");   // tile 0 landed
  __builtin_amdgcn_sched_barrier(0);
  loadK(bufp(0), kf0); loadV(bufp(0), vf0);

  for (int kt = 0; kt < 32; kt += 2) {
    const char* sb1 = bufp((kt + 1) % 3);
    const char* sb2 = bufp((kt + 2) % 3);

    // ---- QK even tile (regs preloaded) ----
    f32x4 sa0[8] = {};
    qk(kf0, sa0);

    // stage kt+3 into buf kt%3 (kf0/vf0 reads retired via qk's lgkm wait)
    asm volatile("s_waitcnt lgkmcnt(0)" ::: "memory");
    __builtin_amdgcn_sched_barrier(0);
    stage((kt + 3) & 31, kt % 3);

    // wait tile kt+1 landed; prefetch its regs (overlaps exp2 below)
    asm volatile("s_waitcnt vmcnt(8)" ::: "memory");
    __builtin_amdgcn_sched_barrier(0);
    loadK(sb1, kf1); loadV(sb1, vf1);

    bf16x4 pb0[8];
    expcvt(sa0, pb0);

    // ---- QK odd tile ----
    f32x4 sa1[8] = {};
    qk(kf1, sa1);

    // stage kt+4 into buf (kt+1)%3
    asm volatile("s_waitcnt lgkmcnt(0)" ::: "memory");
    __builtin_amdgcn_sched_barrier(0);
    stage((kt + 4) & 31, (kt + 1) % 3);

    // wait tile kt+2 landed; prefetch next even tile's regs (overlaps exp2+PV)
    asm volatile("s_waitcnt vmcnt(8)" ::: "memory");
    __builtin_amdgcn_sched_barrier(0);
    if (kt < 30) { loadK(sb2, kfn); loadV(sb2, vfn); }

    bf16x4 pb1[8];
    expcvt(sa1, pb1);

    // ---- PV pair: K=32, slots [even k(4g..4g+3) | odd k(4g..4g+3)] ----
    bf16x8 pvv[8];
#pragma unroll
    for (int jq = 0; jq < 8; ++jq) pvv[jq] = cat4(pb0[jq], pb1[jq]);
    __builtin_amdgcn_s_setprio(1);
#pragma unroll
    for (int dn = 0; dn < 4; ++dn) {
      const bf16x8 av = cat4(vf0[dn], vf1[dn]);
#pragma unroll
      for (int jq = 0; jq < 8; ++jq)
        o_acc[dn][jq] = __builtin_amdgcn_mfma_f32_16x16x32_bf16(av, pvv[jq], o_acc[dn][jq], 0, 0, 0);
    }
    __builtin_amdgcn_s_setprio(0);

    // rotate prefetched regs
    kf0[0] = kfn[0]; kf0[1] = kfn[1];
#pragma unroll
    for (int dn = 0; dn < 4; ++dn) vf0[dn] = vfn[dn];
  }

  // drain wrapped prefetch stages before pool reuse (per-wave), then sync all
  asm volatile("s_waitcnt vmcnt(0)" ::: "memory");
  __builtin_amdgcn_sched_barrier(0);
  __syncthreads();

  // ---- epilogue: l reduce + cross-wave O reduction in two q-halves ----
  float* sA = (float*)pool;                    // [64][68] f32 = 17408 B
  float* sB = (float*)(pool + 17408);          // [64][68] f32
  float* lsumP = (float*)(pool + 34816);       // [4][128] f32 = 2048 B
#pragma unroll
  for (int jq = 0; jq < 8; ++jq) {
    float v = l_p[jq];
    v += __shfl_xor(v, 16);
    v += __shfl_xor(v, 32);
    if (g == 0) lsumP[wid * 128 + jq * 16 + c] = v;
  }

  auto writeO = [&](float* s, int jb) {
#pragma unroll
    for (int dn = 0; dn < 4; ++dn)
#pragma unroll
      for (int j = 0; j < 4; ++j)
        *reinterpret_cast<f32x4*>(&s[(j * 16 + c) * 68 + dn * 16 + 4 * g]) = o_acc[dn][jb + j];
  };
  auto addO = [&](float* s, int jb) {
#pragma unroll
    for (int dn = 0; dn < 4; ++dn)
#pragma unroll
      for (int j = 0; j < 4; ++j)
        o_acc[dn][jb + j] += *reinterpret_cast<const f32x4*>(&s[(j * 16 + c) * 68 + dn * 16 + 4 * g]);
  };

  const int b = bh / NH, h = bh % NH;
#pragma unroll
  for (int half = 0; half < 2; ++half) {
    const int jb = half * 4;
    if (half) __syncthreads();
    if (wid == 1) writeO(sA, jb);
    __syncthreads();
    if (wid == 2) writeO(sB, jb);
    if (wid == 0) addO(sA, jb);
    __syncthreads();
    if (wid == 3) writeO(sA, jb);
    if (wid == 0) addO(sB, jb);
    __syncthreads();
    if (wid == 0) {
      addO(sA, jb);
      float linv[4];
#pragma unroll
      for (int j = 0; j < 4; ++j) {
        const int q = (jb + j) * 16 + c;
        const float l = (lsumP[q] + lsumP[128 + q]) + (lsumP[256 + q] + lsumP[384 + q]);
        linv[j] = __builtin_amdgcn_rcpf(l);
      }
#pragma unroll
      for (int dn = 0; dn < 4; ++dn)
#pragma unroll
        for (int j = 0; j < 4; ++j) {
          uint2 wv = make_uint2(
              cvt_pk_bf16(o_acc[dn][jb + j][0] * linv[j], o_acc[dn][jb + j][1] * linv[j]),
              cvt_pk_bf16(o_acc[dn][jb + j][2] * linv[j], o_acc[dn][jb + j][3] * linv[j]));
          *reinterpret_cast<uint2*>(
              &ao[((size_t)b * SEQ + qs0 + (jb + j) * 16 + c) * DM + h * HD + dn * 16 + 4 * g]) = wv;
        }
    }
  }
}

// ---------------------------------------------------------------------------
// Kernel 3: out = ao @ pwb^T + proj_b  (bf16 inputs, f32 out).
// ---------------------------------------------------------------------------
__global__ __launch_bounds__(256) void proj_kernel(
    const unsigned short* __restrict__ ao, const unsigned short* __restrict__ pwb,
    const float* __restrict__ bias, float* __restrict__ out) {
  __shared__ alignas(16) unsigned short As[128 * 40];
  __shared__ alignas(16) unsigned short Bs[128 * 40];
  const int tid = threadIdx.x;
  const int lane = tid & 63, wid = tid >> 6;
  const int wr = wid >> 1, wc = wid & 1;
  const int g = lane >> 4, c = lane & 15;
  const int m0 = blockIdx.x * 128, n0 = blockIdx.y * 128;

  f32x4 acc[4][4] = {};

  for (int k0 = 0; k0 < DM; k0 += 32) {
#pragma unroll
    for (int i = 0; i < 2; ++i) {
      const int idx = tid + i * 256;
      const int row = idx >> 2, kq = (idx & 3) << 3;
      *reinterpret_cast<bf16x8*>(&As[row * 40 + kq]) =
          *reinterpret_cast<const bf16x8*>(&ao[(m0 + row) * DM + k0 + kq]);
      *reinterpret_cast<bf16x8*>(&Bs[row * 40 + kq]) =
          *reinterpret_cast<const bf16x8*>(&pwb[(n0 + row) * DM + k0 + kq]);
    }
    __syncthreads();
    bf16x8 a_f[4], b_f[4];
#pragma unroll
    for (int i = 0; i < 4; ++i) {
      a_f[i] = *reinterpret_cast<const bf16x8*>(&As[(wr * 64 + i * 16 + c) * 40 + g * 8]);
      b_f[i] = *reinterpret_cast<const bf16x8*>(&Bs[(wc * 64 + i * 16 + c) * 40 + g * 8]);
    }
#pragma unroll
    for (int ai = 0; ai < 4; ++ai)
#pragma unroll
      for (int ni = 0; ni < 4; ++ni)
        acc[ai][ni] = __builtin_amdgcn_mfma_f32_16x16x32_bf16(a_f[ai], b_f[ni], acc[ai][ni], 0, 0, 0);
    __syncthreads();
  }

#pragma unroll
  for (int ni = 0; ni < 4; ++ni) {
    const int n = n0 + wc * 64 + ni * 16 + c;
    const float bn = bias[n];
#pragma unroll
    for (int ai = 0; ai < 4; ++ai)
#pragma unroll
      for (int r = 0; r < 4; ++r) {
        const int m = m0 + wr * 64 + ai * 16 + g * 4 + r;
        out[(size_t)m * DM + n] = acc[ai][ni][r] + bn;
      }
  }
}

extern "C" void kernel_launch(void* const* d_in, const int* in_sizes, int n_in,
                              void* d_out, int out_size, void* d_ws, size_t ws_size,
                              hipStream_t stream) {
  const float* x = (const float*)d_in[0];
  const float* qkv_w = (const float*)d_in[1];
  const float* qkv_b = (const float*)d_in[2];
  const float* proj_w = (const float*)d_in[3];
  const float* proj_b = (const float*)d_in[4];
  float* out = (float*)d_out;

  const size_t elems = (size_t)4 * NH * SEQ * HD;  // 6291456 = B*S*DM
  unsigned short* qbuf = (unsigned short*)d_ws;
  unsigned short* vtbuf = qbuf + elems;
  unsigned short* xbf = vtbuf + elems;       // aliases aobuf (disjoint lifetimes)
  unsigned short* aobuf = xbf;
  unsigned short* wqkvbf = xbf + elems;      // 1179648
  unsigned short* wprojbf = wqkvbf + (size_t)2 * DM * DM;  // 589824

  cvt_kernel<<<dim3(1024), 256, 0, stream>>>(x, xbf, (int)(elems / 8));
  cvt_kernel<<<dim3(576), 256, 0, stream>>>(qkv_w, wqkvbf, 2 * DM * DM / 8);
  cvt_kernel<<<dim3(288), 256, 0, stream>>>(proj_w, wprojbf, DM * DM / 8);

  qkv_kernel<<<dim3(64, 12), 256, 0, stream>>>(xbf, wqkvbf, qkv_b, qbuf, vtbuf);
  attn_kernel<<<dim3(16, 48), 256, 0, stream>>>(qbuf, vtbuf, aobuf);
  proj_kernel<<<dim3(64, 6), 256, 0, stream>>>(aobuf, wprojbf, proj_b, out);
}